// Round 12
// baseline (466.712 us; speedup 1.0000x reference)
//
#include <hip/hip_runtime.h>
#include <hip/hip_fp16.h>

// Problem constants (from reference setup_inputs)
#define N_TOK 65536
#define KNB 32
#define DIM 128
#define BETA 0.5f
// RHO == 1.0f folded into the arithmetic.

// ---- pre-pass: M fp32 -> fp16 (RNE). ~48 MB traffic, ~8 us. ----
__global__ __launch_bounds__(256) void convert_m(
    const float4* __restrict__ in, __half2* __restrict__ out, int n4)
{
    const int i = blockIdx.x * 256 + threadIdx.x;
    if (i < n4) {
        const float4 f = in[i];
        out[2 * i]     = __floats2half2_rn(f.x, f.y);
        out[2 * i + 1] = __floats2half2_rn(f.z, f.w);
    }
}

static __device__ __forceinline__ float2 h2f(unsigned int h) {
    return __half22float2(__builtin_bit_cast(__half2, h));
}

// ONE wave per row; lane owns dims (2*lane, 2*lane+1) via one 4-byte half2
// gather. ALL ALU in fp32 (r11 proved fp16 vector ALU scalarizes: 103%
// VALUBusy, 4.4x regression). The gathered tile is staged in wave-private
// LDS [k][lane] (bank-perfect, no barriers) instead of registers: r9's
// VGPR_Count=60 showed t[32] was AGPR-parked, costing ~192 v_accvgpr moves
// per wave and capping occupancy at 39%.
__global__ __launch_bounds__(256) void mirror_main(
    const unsigned int* __restrict__ M16,   // half2 pairs as raw u32
    const float*        __restrict__ P,
    const float*        __restrict__ Y,
    const float*        __restrict__ Lam,
    const int*          __restrict__ Kset,
    float* __restrict__ Pnew,
    float* __restrict__ LamNew,
    float* __restrict__ blockPartials)
{
    const int wid  = threadIdx.x >> 6;     // wave id in block (0..3)
    const int lane = threadIdx.x & 63;
    const int n    = blockIdx.x * 4 + wid; // row index
    const int d0   = lane * 2;

    __shared__ unsigned int tlds[4][KNB][64];   // 32 KB/block, wave-private

    const float2 y   = *(const float2*)&Y[n * DIM + d0];
    const float2 lam = *(const float2*)&Lam[n * DIM + d0];

    const int*   ks   = &Kset[n * KNB];    // wave-uniform -> s_load
    const float* prow = &P[n * KNB];       // wave-uniform -> s_load

    // ---- single gather: stage raw half2 into LDS, accumulate Y_from_P ----
    float ypx = 0.f, ypy = 0.f;
    #pragma unroll
    for (int k = 0; k < KNB; ++k) {
        const int idx = ks[k];
        const unsigned int h = M16[(size_t)idx * (DIM / 2) + lane];
        tlds[wid][k][lane] = h;
        const float2 tf = h2f(h);
        const float pk = prow[k];
        ypx = fmaf(pk, tf.x, ypx);
        ypy = fmaf(pk, tf.y, ypy);
    }
    // Force the compiler to forget the gathered registers; later phases must
    // read back from LDS (prevents AGPR parking of a 64-reg live tile).
    asm volatile("" ::: "memory");

    // xi = lam + rho*(y - yp)   (RHO = 1)
    const float xix = lam.x + (y.x - ypx);
    const float xiy = lam.y + (y.y - ypy);

    // ---- per-lane score partials from LDS ----
    float v[KNB];
    #pragma unroll
    for (int k = 0; k < KNB; ++k) {
        const float2 tf = h2f(tlds[wid][k][lane]);
        v[k] = tf.x * xix + tf.y * xiy;
    }

    // ---- reduce-scatter: 32 shuffles; lane l ends with full score k=(l>>1)
    #pragma unroll
    for (int dd = 32; dd >= 2; dd >>= 1) {
        const int hw = dd >> 1;
        const bool upper = (lane & dd) != 0;
        #pragma unroll
        for (int j = 0; j < hw; ++j) {
            const float send = upper ? v[j] : v[j + hw];
            const float keep = upper ? v[j + hw] : v[j];
            const float recv = __shfl_xor(send, dd, 64);
            v[j] = keep + recv;
        }
    }
    const float S = v[0] + __shfl_xor(v[0], 1, 64);
    const int myk = lane >> 1;

    // ---- distributed softmax: softmax(log P - beta*S)
    //      == P*exp(-beta*(S-m))/sum; k lives on lane pairs (dist 2..32).
    float m = S;
    #pragma unroll
    for (int dd = 2; dd <= 32; dd <<= 1)
        m = fminf(m, __shfl_xor(m, dd, 64));

    const float pk_mine = prow[myk];
    float e = pk_mine * __expf(-BETA * (S - m));
    float esum = e;
    #pragma unroll
    for (int dd = 2; dd <= 32; dd <<= 1)
        esum += __shfl_xor(esum, dd, 64);

    const float inv = 1.f / esum;
    const float pn_mine = e * inv;

    // compact k -> lanes 0..31, one coalesced 128 B store
    const float pn_compact = __shfl(pn_mine, lane * 2, 64);
    if (lane < KNB)
        Pnew[n * KNB + lane] = pn_compact;

    // ---- pass 2: Y_from_Pnew from LDS; readlane(2k) -> SGPR broadcast ----
    float yp2x = 0.f, yp2y = 0.f;
    #pragma unroll
    for (int k = 0; k < KNB; ++k) {
        const float pn = __uint_as_float(
            __builtin_amdgcn_readlane(__float_as_uint(pn_mine), 2 * k));
        const float2 tf = h2f(tlds[wid][k][lane]);
        yp2x = fmaf(pn, tf.x, yp2x);
        yp2y = fmaf(pn, tf.y, yp2y);
    }

    const float rx = y.x - yp2x;
    const float ry = y.y - yp2y;
    const float lnx = lam.x + rx;          // RHO = 1
    const float lny = lam.y + ry;
    *(float2*)&LamNew[n * DIM + d0] = make_float2(lnx, lny);

    // energy: 0.5*r^2 + ln*r over this lane's 2 dims; wave then block sum.
    float c = 0.5f * (rx * rx + ry * ry) + lnx * rx + lny * ry;
    #pragma unroll
    for (int dd = 1; dd <= 32; dd <<= 1)
        c += __shfl_xor(c, dd, 64);

    __shared__ float wsum[4];
    if (lane == 0) wsum[wid] = c;
    __syncthreads();
    if (threadIdx.x == 0)
        blockPartials[blockIdx.x] = wsum[0] + wsum[1] + wsum[2] + wsum[3];
}

// Single-kernel deterministic reduction of 16384 partials.
__global__ __launch_bounds__(256) void reduce_energy(
    const float4* __restrict__ in, float* __restrict__ out)
{
    float acc = 0.f;
    #pragma unroll
    for (int i = 0; i < 16; ++i) {
        const float4 f = in[threadIdx.x + 256 * i];
        acc += (f.x + f.y) + (f.z + f.w);
    }
    __shared__ float s[256];
    s[threadIdx.x] = acc;
    __syncthreads();
    for (int sft = 128; sft > 0; sft >>= 1) {
        if (threadIdx.x < sft) s[threadIdx.x] += s[threadIdx.x + sft];
        __syncthreads();
    }
    if (threadIdx.x == 0) out[0] = s[0];
}

extern "C" void kernel_launch(void* const* d_in, const int* in_sizes, int n_in,
                              void* d_out, int out_size, void* d_ws, size_t ws_size,
                              hipStream_t stream) {
    // inputs in setup_inputs() dict order: M, P, Y, Lam, Kset
    const float* M    = (const float*)d_in[0];
    const float* P    = (const float*)d_in[1];
    const float* Y    = (const float*)d_in[2];
    const float* Lam  = (const float*)d_in[3];
    const int*   Kset = (const int*)d_in[4];

    float* out    = (float*)d_out;
    float* Pnew   = out;                               // N*K floats
    float* LamNew = out + (size_t)N_TOK * KNB;         // N*D floats
    float* energy = out + (size_t)N_TOK * KNB + (size_t)N_TOK * DIM; // 1 float

    const int nBlocks = N_TOK / 4;                     // 16384 (4 rows/block)
    const size_t m16Bytes = (size_t)N_TOK * DIM * 2;   // 16.78 MB
    unsigned int* M16 = (unsigned int*)d_ws;
    float* blockPartials = (float*)((char*)d_ws + m16Bytes);      // 16384 f

    const int n4 = N_TOK * DIM / 4;                    // 2.1M float4s
    convert_m<<<(n4 + 255) / 256, 256, 0, stream>>>(
        (const float4*)M, (__half2*)M16, n4);
    mirror_main<<<nBlocks, 256, 0, stream>>>(
        M16, P, Y, Lam, Kset, Pnew, LamNew, blockPartials);
    reduce_energy<<<1, 256, 0, stream>>>((const float4*)blockPartials, energy);
}

// Round 13
// 431.228 us; speedup vs baseline: 1.0823x; 1.0823x over previous
//
#include <hip/hip_runtime.h>
#include <hip/hip_fp16.h>

// Problem constants (from reference setup_inputs)
#define N_TOK 65536
#define KNB 32
#define DIM 128
#define BETA 0.5f
// RHO == 1.0f folded into the arithmetic.

// ---- pre-pass: M fp32 -> fp16 (RNE). ~48 MB traffic, ~8 us. ----
__global__ __launch_bounds__(256) void convert_m(
    const float4* __restrict__ in, __half2* __restrict__ out, int n4)
{
    const int i = blockIdx.x * 256 + threadIdx.x;
    if (i < n4) {
        const float4 f = in[i];
        out[2 * i]     = __floats2half2_rn(f.x, f.y);
        out[2 * i + 1] = __floats2half2_rn(f.z, f.w);
    }
}

static __device__ __forceinline__ float2 h2f(unsigned int h) {
    return __half22float2(__builtin_bit_cast(__half2, h));
}

// ONE wave per row; lane owns dims (2*lane, 2*lane+1) via one 4-byte half2
// gather. Identical structure to the 96.7us r9 kernel with ONE change:
// the tile is held as raw u32 half2 in 32 VGPRs (r9's float2 t[32] needed
// 64 regs -> AGPR-parked at VGPR_Count=60, ~192 v_accvgpr moves/wave,
// occupancy capped at 39%). Convert on use: 2x v_cvt_f32_f16 per k per
// site, replacing the AGPR moves 1:1. ALU stays scalar fp32 (r11 lesson);
// no LDS staging, no memory clobber (r12 lesson).
__global__ __launch_bounds__(256, 4) void mirror_main(
    const unsigned int* __restrict__ M16,   // half2 pairs as raw u32
    const float*        __restrict__ P,
    const float*        __restrict__ Y,
    const float*        __restrict__ Lam,
    const int*          __restrict__ Kset,
    float* __restrict__ Pnew,
    float* __restrict__ LamNew,
    float* __restrict__ blockPartials)
{
    const int wid  = threadIdx.x >> 6;     // wave id in block (0..3)
    const int lane = threadIdx.x & 63;
    const int n    = blockIdx.x * 4 + wid; // row index
    const int d0   = lane * 2;

    const float2 y   = *(const float2*)&Y[n * DIM + d0];
    const float2 lam = *(const float2*)&Lam[n * DIM + d0];

    const int*   ks   = &Kset[n * KNB];    // wave-uniform -> s_load
    const float* prow = &P[n * KNB];       // wave-uniform -> s_load

    // ---- single gather: raw half2 into 32 VGPRs, accumulate Y_from_P ----
    unsigned int traw[KNB];
    float ypx = 0.f, ypy = 0.f;
    #pragma unroll
    for (int k = 0; k < KNB; ++k) {
        const int idx = ks[k];
        traw[k] = M16[(size_t)idx * (DIM / 2) + lane];
        asm("" : "+v"(traw[k]));           // keep resident; no re-gather
        const float2 tf = h2f(traw[k]);
        const float pk = prow[k];
        ypx = fmaf(pk, tf.x, ypx);
        ypy = fmaf(pk, tf.y, ypy);
    }

    // xi = lam + rho*(y - yp)   (RHO = 1)
    const float xix = lam.x + (y.x - ypx);
    const float xiy = lam.y + (y.y - ypy);

    // ---- per-lane score partials (cvt on use) ----
    float v[KNB];
    #pragma unroll
    for (int k = 0; k < KNB; ++k) {
        const float2 tf = h2f(traw[k]);
        v[k] = tf.x * xix + tf.y * xiy;
    }

    // ---- reduce-scatter: 32 shuffles; lane l ends with full score k=(l>>1)
    #pragma unroll
    for (int dd = 32; dd >= 2; dd >>= 1) {
        const int hw = dd >> 1;
        const bool upper = (lane & dd) != 0;
        #pragma unroll
        for (int j = 0; j < hw; ++j) {
            const float send = upper ? v[j] : v[j + hw];
            const float keep = upper ? v[j + hw] : v[j];
            const float recv = __shfl_xor(send, dd, 64);
            v[j] = keep + recv;
        }
    }
    const float S = v[0] + __shfl_xor(v[0], 1, 64);
    const int myk = lane >> 1;

    // ---- distributed softmax: softmax(log P - beta*S)
    //      == P*exp(-beta*(S-m))/sum; k lives on lane pairs (dist 2..32).
    float m = S;
    #pragma unroll
    for (int dd = 2; dd <= 32; dd <<= 1)
        m = fminf(m, __shfl_xor(m, dd, 64));

    const float pk_mine = prow[myk];
    float e = pk_mine * __expf(-BETA * (S - m));
    float esum = e;
    #pragma unroll
    for (int dd = 2; dd <= 32; dd <<= 1)
        esum += __shfl_xor(esum, dd, 64);

    const float inv = 1.f / esum;
    const float pn_mine = e * inv;

    // compact k -> lanes 0..31, one coalesced 128 B store
    const float pn_compact = __shfl(pn_mine, lane * 2, 64);
    if (lane < KNB)
        Pnew[n * KNB + lane] = pn_compact;

    // ---- pass 2: Y_from_Pnew (cvt on use); readlane(2k) -> SGPR bcast ----
    float yp2x = 0.f, yp2y = 0.f;
    #pragma unroll
    for (int k = 0; k < KNB; ++k) {
        const float pn = __uint_as_float(
            __builtin_amdgcn_readlane(__float_as_uint(pn_mine), 2 * k));
        const float2 tf = h2f(traw[k]);
        yp2x = fmaf(pn, tf.x, yp2x);
        yp2y = fmaf(pn, tf.y, yp2y);
    }

    const float rx = y.x - yp2x;
    const float ry = y.y - yp2y;
    const float lnx = lam.x + rx;          // RHO = 1
    const float lny = lam.y + ry;
    *(float2*)&LamNew[n * DIM + d0] = make_float2(lnx, lny);

    // energy: 0.5*r^2 + ln*r over this lane's 2 dims; wave then block sum.
    float c = 0.5f * (rx * rx + ry * ry) + lnx * rx + lny * ry;
    #pragma unroll
    for (int dd = 1; dd <= 32; dd <<= 1)
        c += __shfl_xor(c, dd, 64);

    __shared__ float wsum[4];
    if (lane == 0) wsum[wid] = c;
    __syncthreads();
    if (threadIdx.x == 0)
        blockPartials[blockIdx.x] = wsum[0] + wsum[1] + wsum[2] + wsum[3];
}

// Single-kernel deterministic reduction of 16384 partials.
__global__ __launch_bounds__(256) void reduce_energy(
    const float4* __restrict__ in, float* __restrict__ out)
{
    float acc = 0.f;
    #pragma unroll
    for (int i = 0; i < 16; ++i) {
        const float4 f = in[threadIdx.x + 256 * i];
        acc += (f.x + f.y) + (f.z + f.w);
    }
    __shared__ float s[256];
    s[threadIdx.x] = acc;
    __syncthreads();
    for (int sft = 128; sft > 0; sft >>= 1) {
        if (threadIdx.x < sft) s[threadIdx.x] += s[threadIdx.x + sft];
        __syncthreads();
    }
    if (threadIdx.x == 0) out[0] = s[0];
}

extern "C" void kernel_launch(void* const* d_in, const int* in_sizes, int n_in,
                              void* d_out, int out_size, void* d_ws, size_t ws_size,
                              hipStream_t stream) {
    // inputs in setup_inputs() dict order: M, P, Y, Lam, Kset
    const float* M    = (const float*)d_in[0];
    const float* P    = (const float*)d_in[1];
    const float* Y    = (const float*)d_in[2];
    const float* Lam  = (const float*)d_in[3];
    const int*   Kset = (const int*)d_in[4];

    float* out    = (float*)d_out;
    float* Pnew   = out;                               // N*K floats
    float* LamNew = out + (size_t)N_TOK * KNB;         // N*D floats
    float* energy = out + (size_t)N_TOK * KNB + (size_t)N_TOK * DIM; // 1 float

    const int nBlocks = N_TOK / 4;                     // 16384 (4 rows/block)
    const size_t m16Bytes = (size_t)N_TOK * DIM * 2;   // 16.78 MB
    unsigned int* M16 = (unsigned int*)d_ws;
    float* blockPartials = (float*)((char*)d_ws + m16Bytes);      // 16384 f

    const int n4 = N_TOK * DIM / 4;                    // 2.1M float4s
    convert_m<<<(n4 + 255) / 256, 256, 0, stream>>>(
        (const float4*)M, (__half2*)M16, n4);
    mirror_main<<<nBlocks, 256, 0, stream>>>(
        M16, P, Y, Lam, Kset, Pnew, LamNew, blockPartials);
    reduce_energy<<<1, 256, 0, stream>>>((const float4*)blockPartials, energy);
}

// Round 14
// 96.714 us; speedup vs baseline: 4.8257x; 4.4588x over previous
//
#include <hip/hip_runtime.h>
#include <hip/hip_fp16.h>

// Problem constants (from reference setup_inputs)
#define N_TOK 65536
#define KNB 32
#define DIM 128
#define BETA 0.5f
// RHO == 1.0f folded into the arithmetic.

// ---- pre-pass: M fp32 -> fp16 (RNE). ~48 MB traffic, ~8 us. ----
__global__ __launch_bounds__(256) void convert_m(
    const float4* __restrict__ in, __half2* __restrict__ out, int n4)
{
    const int i = blockIdx.x * 256 + threadIdx.x;
    if (i < n4) {
        const float4 f = in[i];
        out[2 * i]     = __floats2half2_rn(f.x, f.y);
        out[2 * i + 1] = __floats2half2_rn(f.z, f.w);
    }
}

// ONE wave per row. Lane owns dims (2*lane, 2*lane+1) via one __half2 gather
// (4 B/lane -> 256 B/wave). fp16 is STORAGE ONLY; all ALU scalar fp32.
// NOTE (r11-r13 post-mortem): t[32] float2 living partly in AGPRs at
// VGPR_Count=60 is the GOOD outcome — the unified file's AGPR half doubles
// register capacity and v_accvgpr moves are full-rate. Attempts to "fix" it
// (packed-u32 pinning, LDS staging, fp16 vector ALU) all pushed arrays to
// scratch: 4.5x regressions with VALUBusy >100%. Do not restructure.
__global__ __launch_bounds__(256, 4) void mirror_main(
    const __half2* __restrict__ M16,
    const float*   __restrict__ P,
    const float*   __restrict__ Y,
    const float*   __restrict__ Lam,
    const int*     __restrict__ Kset,
    float* __restrict__ Pnew,
    float* __restrict__ LamNew,
    float* __restrict__ blockPartials)
{
    const int wid  = threadIdx.x >> 6;     // wave id in block (0..3)
    const int lane = threadIdx.x & 63;
    const int n    = blockIdx.x * 4 + wid; // row index
    const int d0   = lane * 2;

    const float2 y   = *(const float2*)&Y[n * DIM + d0];
    const float2 lam = *(const float2*)&Lam[n * DIM + d0];

    const int*   ks   = &Kset[n * KNB];    // wave-uniform -> s_load
    const float* prow = &P[n * KNB];       // wave-uniform -> s_load

    // ---- single gather: T into registers, accumulate Y_from_P ----
    float2 t[KNB];
    float ypx = 0.f, ypy = 0.f;
    #pragma unroll
    for (int k = 0; k < KNB; ++k) {
        const int idx = ks[k];
        const __half2 h = M16[(size_t)idx * (DIM / 2) + lane];
        t[k] = __half22float2(h);
        asm("" : "+v"(t[k].x), "+v"(t[k].y));  // forbid re-gather remat
        const float pk = prow[k];
        ypx = fmaf(pk, t[k].x, ypx);
        ypy = fmaf(pk, t[k].y, ypy);
    }

    // xi = lam + rho*(y - yp)   (RHO = 1)
    const float xix = lam.x + (y.x - ypx);
    const float xiy = lam.y + (y.y - ypy);

    // ---- per-lane score partials ----
    float v[KNB];
    #pragma unroll
    for (int k = 0; k < KNB; ++k)
        v[k] = t[k].x * xix + t[k].y * xiy;

    // ---- reduce-scatter: 32 shuffles; lane l ends with full score k=(l>>1)
    #pragma unroll
    for (int dd = 32; dd >= 2; dd >>= 1) {
        const int hw = dd >> 1;
        const bool upper = (lane & dd) != 0;
        #pragma unroll
        for (int j = 0; j < hw; ++j) {
            const float send = upper ? v[j] : v[j + hw];
            const float keep = upper ? v[j + hw] : v[j];
            const float recv = __shfl_xor(send, dd, 64);
            v[j] = keep + recv;
        }
    }
    const float S = v[0] + __shfl_xor(v[0], 1, 64);
    const int myk = lane >> 1;

    // ---- distributed softmax: softmax(log P - beta*S)
    //      == P*exp(-beta*(S-m))/sum; k lives on lane pairs (dist 2..32).
    float m = S;
    #pragma unroll
    for (int dd = 2; dd <= 32; dd <<= 1)
        m = fminf(m, __shfl_xor(m, dd, 64));

    const float pk_mine = prow[myk];
    float e = pk_mine * __expf(-BETA * (S - m));
    float esum = e;
    #pragma unroll
    for (int dd = 2; dd <= 32; dd <<= 1)
        esum += __shfl_xor(esum, dd, 64);

    const float inv = 1.f / esum;
    const float pn_mine = e * inv;

    // compact k -> lanes 0..31, one coalesced 128 B store
    const float pn_compact = __shfl(pn_mine, lane * 2, 64);
    if (lane < KNB)
        Pnew[n * KNB + lane] = pn_compact;

    // ---- pass 2: Y_from_Pnew. readlane(2k) -> SGPR broadcast. ----
    float yp2x = 0.f, yp2y = 0.f;
    #pragma unroll
    for (int k = 0; k < KNB; ++k) {
        const float pn = __uint_as_float(
            __builtin_amdgcn_readlane(__float_as_uint(pn_mine), 2 * k));
        yp2x = fmaf(pn, t[k].x, yp2x);
        yp2y = fmaf(pn, t[k].y, yp2y);
    }

    const float rx = y.x - yp2x;
    const float ry = y.y - yp2y;
    const float lnx = lam.x + rx;          // RHO = 1
    const float lny = lam.y + ry;
    *(float2*)&LamNew[n * DIM + d0] = make_float2(lnx, lny);

    // energy: 0.5*r^2 + ln*r over this lane's 2 dims; wave then block sum.
    float c = 0.5f * (rx * rx + ry * ry) + lnx * rx + lny * ry;
    #pragma unroll
    for (int dd = 1; dd <= 32; dd <<= 1)
        c += __shfl_xor(c, dd, 64);

    __shared__ float wsum[4];
    if (lane == 0) wsum[wid] = c;
    __syncthreads();
    if (threadIdx.x == 0)
        blockPartials[blockIdx.x] = wsum[0] + wsum[1] + wsum[2] + wsum[3];
}

// Single-kernel deterministic reduction of 16384 partials.
__global__ __launch_bounds__(256) void reduce_energy(
    const float4* __restrict__ in, float* __restrict__ out)
{
    float acc = 0.f;
    #pragma unroll
    for (int i = 0; i < 16; ++i) {
        const float4 f = in[threadIdx.x + 256 * i];
        acc += (f.x + f.y) + (f.z + f.w);
    }
    __shared__ float s[256];
    s[threadIdx.x] = acc;
    __syncthreads();
    for (int sft = 128; sft > 0; sft >>= 1) {
        if (threadIdx.x < sft) s[threadIdx.x] += s[threadIdx.x + sft];
        __syncthreads();
    }
    if (threadIdx.x == 0) out[0] = s[0];
}

extern "C" void kernel_launch(void* const* d_in, const int* in_sizes, int n_in,
                              void* d_out, int out_size, void* d_ws, size_t ws_size,
                              hipStream_t stream) {
    // inputs in setup_inputs() dict order: M, P, Y, Lam, Kset
    const float* M    = (const float*)d_in[0];
    const float* P    = (const float*)d_in[1];
    const float* Y    = (const float*)d_in[2];
    const float* Lam  = (const float*)d_in[3];
    const int*   Kset = (const int*)d_in[4];

    float* out    = (float*)d_out;
    float* Pnew   = out;                               // N*K floats
    float* LamNew = out + (size_t)N_TOK * KNB;         // N*D floats
    float* energy = out + (size_t)N_TOK * KNB + (size_t)N_TOK * DIM; // 1 float

    const int nBlocks = N_TOK / 4;                     // 16384 (4 rows/block)
    const size_t m16Bytes = (size_t)N_TOK * DIM * sizeof(__half); // 16.78 MB
    __half2* M16 = (__half2*)d_ws;
    float* blockPartials = (float*)((char*)d_ws + m16Bytes);      // 16384 f

    const int n4 = N_TOK * DIM / 4;                    // 2.1M float4s
    convert_m<<<(n4 + 255) / 256, 256, 0, stream>>>(
        (const float4*)M, M16, n4);
    mirror_main<<<nBlocks, 256, 0, stream>>>(
        M16, P, Y, Lam, Kset, Pnew, LamNew, blockPartials);
    reduce_energy<<<1, 256, 0, stream>>>((const float4*)blockPartials, energy);
}